// Round 1
// 2490.585 us; speedup vs baseline: 1.2178x; 1.2178x over previous
//
#include <hip/hip_runtime.h>
#include <hip/hip_bf16.h>
#include <cstdint>

#define TT 128
#define BB 64
#define II 1024
#define HD 4096
#define N_IH 262144
#define N_HH 1048576
#define LN_EPS 1e-5f
#define NREP 16

typedef unsigned int u32;
typedef unsigned short u16;
typedef float f32x2 __attribute__((ext_vector_type(2)));

__device__ __forceinline__ u32 f2bf_bits(float f) {
  u32 u = __float_as_uint(f);
  return (u + 0x7FFFu + ((u >> 16) & 1u)) >> 16;   // RTNE, finite inputs
}

// ---------------- preprocessing ----------------

// replicated histogram: hist[row*64 + rep], rep = blockIdx & 63
__global__ void k_hist(const int* __restrict__ rows, int n, int* __restrict__ hist) {
  int e = blockIdx.x * 256 + threadIdx.x;
  if (e < n) atomicAdd(&hist[rows[e] * 64 + (blockIdx.x & 63)], 1);
}

// wave per row: padded row total
__global__ __launch_bounds__(256) void k_rowtot(const int* __restrict__ hist, int* __restrict__ rowtot) {
  int w = threadIdx.x >> 6, lane = threadIdx.x & 63;
  int row = blockIdx.x * 4 + w;
  int c = hist[row * 64 + lane];
#pragma unroll
  for (int d = 1; d < 64; d <<= 1) c += __shfl_xor(c, d);
  if (lane == 0) rowtot[row] = (c + 7) & ~7;
}

// one block, 64 threads: exclusive scan of 4096 padded row totals
__global__ void k_scan2(const int* __restrict__ rowtot, int* __restrict__ rp) {
  int lane = threadIdx.x;
  int total = 0;
  for (int j = 0; j < 64; ++j) total += rowtot[lane * 64 + j];
  int x = total;
  for (int d = 1; d < 64; d <<= 1) {
    int y = __shfl_up(x, d, 64);
    if (lane >= d) x += y;
  }
  int run = x - total;
  for (int j = 0; j < 64; ++j) {
    int idx = lane * 64 + j;
    rp[idx] = run;
    run += rowtot[idx];
  }
  if (lane == 63) rp[HD] = run;
}

// wave per row: cur[row*64+rep] = rp[row] + exclusive_scan(hist[row][*])
__global__ __launch_bounds__(256) void k_repbase(const int* __restrict__ hist, const int* __restrict__ rp,
                                                 int* __restrict__ cur) {
  int w = threadIdx.x >> 6, lane = threadIdx.x & 63;
  int row = blockIdx.x * 4 + w;
  int c = hist[row * 64 + lane];
  int x = c;
#pragma unroll
  for (int d = 1; d < 64; d <<= 1) {
    int y = __shfl_up(x, d, 64);
    if (lane >= d) x += y;
  }
  cur[row * 64 + lane] = rp[row] + (x - c);
}

__global__ void k_scatter(const int* __restrict__ rows, const int* __restrict__ cols,
                          const float* __restrict__ vals, int n,
                          int* __restrict__ cur, u32* __restrict__ meta,
                          const float* __restrict__ gamma, const float* __restrict__ beta,
                          float* __restrict__ rvg_rep, float* __restrict__ rvb_rep, int fold) {
  int e = blockIdx.x * 256 + threadIdx.x;
  if (e >= n) return;
  int rep = blockIdx.x & 63;
  int r = rows[e], c = cols[e];
  float v = vals[e];
  float vg = v;
  if (fold) {
    vg = v * gamma[c];
    atomicAdd(&rvg_rep[r * 64 + rep], vg);
    atomicAdd(&rvb_rep[r * 64 + rep], v * beta[c]);
  }
  u32 word = (f2bf_bits(vg) << 16) | (u32)c;
  int pos = atomicAdd(&cur[r * 64 + rep], 1);
  meta[pos] = word;
}

// wave per row: reduce 64 replicas -> rowvg/rowvb
__global__ __launch_bounds__(256) void k_rvred(const float* __restrict__ rvg_rep,
                                               const float* __restrict__ rvb_rep,
                                               float* __restrict__ rowvg, float* __restrict__ rowvb) {
  int w = threadIdx.x >> 6, lane = threadIdx.x & 63;
  int row = blockIdx.x * 4 + w;
  float a = rvg_rep[row * 64 + lane];
  float b = rvb_rep[row * 64 + lane];
#pragma unroll
  for (int d = 1; d < 64; d <<= 1) { a += __shfl_xor(a, d); b += __shfl_xor(b, d); }
  if (lane == 0) { rowvg[row] = a; rowvb[row] = b; }
}

// x (B,T,I) fp32 -> xt (T,I,B) bf16
__global__ __launch_bounds__(256) void k_xt(const float* __restrict__ x, u16* __restrict__ xt) {
  __shared__ u16 tile[64][66];
  int t = blockIdx.x >> 4, i0 = (blockIdx.x & 15) << 6;
  int w = threadIdx.x >> 6, lane = threadIdx.x & 63;
#pragma unroll
  for (int k = 0; k < 16; ++k) {
    int b = w * 16 + k;
    float v = x[((size_t)b * TT + t) * II + i0 + lane];
    tile[b][lane] = (u16)f2bf_bits(v);
  }
  __syncthreads();
#pragma unroll
  for (int k = 0; k < 16; ++k) {
    int i = w * 16 + k;
    xt[((size_t)t * II + i0 + i) * BB + lane] = tile[lane][i];
  }
}

// ---------------- per-step kernel ----------------

__device__ __forceinline__ uint4 gld(const char* base, u32 m) {
  return *(const uint4*)(base + ((int)(m & 0xFFFFu) << 7));
}

__device__ __forceinline__ void consume(u32 m, uint4 g, f32x2 acc[4]) {
  float vgf = __uint_as_float(m & 0xFFFF0000u);
  f32x2 vg2 = {vgf, vgf};
  f32x2 p0 = {__uint_as_float(g.x << 16), __uint_as_float(g.x & 0xFFFF0000u)};
  f32x2 p1 = {__uint_as_float(g.y << 16), __uint_as_float(g.y & 0xFFFF0000u)};
  f32x2 p2 = {__uint_as_float(g.z << 16), __uint_as_float(g.z & 0xFFFF0000u)};
  f32x2 p3 = {__uint_as_float(g.w << 16), __uint_as_float(g.w & 0xFFFF0000u)};
  acc[0] += vg2 * p0;
  acc[1] += vg2 * p1;
  acc[2] += vg2 * p2;
  acc[3] += vg2 * p3;
}

// 6-deep software pipeline: meta 6 ahead, 5 gathers outstanding.
// Slack reads beyond n land in following rows / zero pad (meta allocs carry >48 dwords slack).
__device__ __forceinline__ void gather6(const u32* __restrict__ mp, int n,
                                        const char* __restrict__ base, f32x2 acc[4]) {
  if (n <= 0) return;
  u32 m0 = mp[0], m1 = mp[8], m2 = mp[16], m3 = mp[24], m4 = mp[32], m5 = mp[40];
  uint4 g0 = gld(base, m0), g1 = gld(base, m1), g2 = gld(base, m2),
        g3 = gld(base, m3), g4 = gld(base, m4);
#pragma unroll 6
  for (int it = 0; it < n; ++it) {
    u32 m6 = mp[(it + 6) * 8];
    uint4 g5 = gld(base, m5);
    consume(m0, g0, acc);
    m0 = m1; m1 = m2; m2 = m3; m3 = m4; m4 = m5; m5 = m6;
    g0 = g1; g1 = g2; g2 = g3; g3 = g4; g4 = g5;
  }
}

// block = 4 waves = 2 rows, 2 waves per row (half each of IH and HH streams).
// grid HD/2 = 2048 blocks -> 8 blocks/CU -> 32 waves/CU.
__global__ __launch_bounds__(256, 8) void k_step(
    const u32* __restrict__ meta_ih, const int* __restrict__ rp_ih,
    const u32* __restrict__ meta_hh, const int* __restrict__ rp_hh,
    const u16* __restrict__ xt_t, const u16* __restrict__ Aprev,
    u16* __restrict__ Acur,
    const float* __restrict__ st_prev, float* __restrict__ st_cur,
    const float* __restrict__ b_ih, const float* __restrict__ b_hh,
    const float* __restrict__ rowvg, const float* __restrict__ rowvb, int first) {
  __shared__ float s_mu[64], s_rs[64], s_sum[64], s_sq[64];
  __shared__ float epil[4][2][64];
  int tid = threadIdx.x;
  int w = tid >> 6, lane = tid & 63;
  if (tid < 64) { s_sum[tid] = 0.f; s_sq[tid] = 0.f; }
  if (!first && tid >= 64 && tid < 128) {
    int b = tid - 64;
    float s = 0.f, q = 0.f;
#pragma unroll
    for (int r2 = 0; r2 < NREP; ++r2) {
      s += st_prev[r2 * 64 + b];
      q += st_prev[NREP * 64 + r2 * 64 + b];
    }
    float mu = s * (1.0f / HD);
    float var = q * (1.0f / HD) - mu * mu;
    s_mu[b] = mu;
    s_rs[b] = rsqrtf(var + LN_EPS);
  }
  // no barrier here: s_mu/s_rs/s_sum are only consumed after the pre-epilogue
  // __syncthreads below; let all waves start their gathers immediately.

  int row = blockIdx.x * 2 + (w >> 1);
  int half = w & 1;
  int grp = lane >> 3;
  int l = lane & 7;

  // ---- IH half ----
  f32x2 acc[4] = {{0,0},{0,0},{0,0},{0,0}};
  {
    int s0 = rp_ih[row];
    int n = (rp_ih[row + 1] - s0) >> 3;
    int nA = (n + 1) >> 1;
    int nn = half ? (n - nA) : nA;
    int sb = s0 + (half ? nA * 8 : 0);
    gather6(meta_ih + sb + grp, nn, (const char*)xt_t + l * 16, acc);
  }
#pragma unroll
  for (int j = 0; j < 4; ++j) {
#pragma unroll
    for (int d = 8; d < 64; d <<= 1) {
      acc[j].x += __shfl_xor(acc[j].x, d);
      acc[j].y += __shfl_xor(acc[j].y, d);
    }
  }
  if (lane < 8) {
#pragma unroll
    for (int j = 0; j < 4; ++j) {
      epil[w][0][lane * 8 + 2 * j] = acc[j].x;
      epil[w][0][lane * 8 + 2 * j + 1] = acc[j].y;
    }
  }

  // ---- HH half ----
#pragma unroll
  for (int j = 0; j < 4; ++j) { acc[j].x = 0.f; acc[j].y = 0.f; }
  if (!first) {
    int s0 = rp_hh[row];
    int n = (rp_hh[row + 1] - s0) >> 3;
    int nA = (n + 1) >> 1;
    int nn = half ? (n - nA) : nA;
    int sb = s0 + (half ? nA * 8 : 0);
    gather6(meta_hh + sb + grp, nn, (const char*)Aprev + l * 16, acc);
  }
#pragma unroll
  for (int j = 0; j < 4; ++j) {
#pragma unroll
    for (int d = 8; d < 64; d <<= 1) {
      acc[j].x += __shfl_xor(acc[j].x, d);
      acc[j].y += __shfl_xor(acc[j].y, d);
    }
  }
  if (lane < 8) {
#pragma unroll
    for (int j = 0; j < 4; ++j) {
      epil[w][1][lane * 8 + 2 * j] = acc[j].x;
      epil[w][1][lane * 8 + 2 * j + 1] = acc[j].y;
    }
  }

  __syncthreads();
  if (tid < 128) {
    int ridx = tid >> 6;
    int b = tid & 63;
    int row_e = blockIdx.x * 2 + ridx;
    float S_ih = epil[ridx * 2][0][b] + epil[ridx * 2 + 1][0][b];
    float bih = b_ih[row_e], bhh = b_hh[row_e];
    float pre;
    if (first) {
      pre = S_ih + bih + bhh;
    } else {
      float S_hh = epil[ridx * 2][1][b] + epil[ridx * 2 + 1][1][b];
      pre = S_ih + s_rs[b] * (S_hh - s_mu[b] * rowvg[row_e]) + (bih + bhh + rowvb[row_e]);
    }
    float h = 1.0f - 2.0f / (__expf(2.0f * pre) + 1.0f);   // tanh
    Acur[(size_t)row_e * BB + b] = (u16)f2bf_bits(h);
    atomicAdd(&s_sum[b], h);
    atomicAdd(&s_sq[b], h * h);
  }
  __syncthreads();
  if (tid < 64) {
    int rep = blockIdx.x & (NREP - 1);
    atomicAdd(&st_cur[rep * 64 + tid], s_sum[tid]);
    atomicAdd(&st_cur[NREP * 64 + rep * 64 + tid], s_sq[tid]);
  }
}

// ---------------- final output ----------------

__global__ __launch_bounds__(256) void k_out(const u16* __restrict__ A,
                                             const float* __restrict__ stats,
                                             const float* __restrict__ gamma,
                                             const float* __restrict__ beta,
                                             float* __restrict__ out) {
  __shared__ float s_mu[64], s_rs[64];
  __shared__ float tile[64][65];
  int t = blockIdx.x >> 6, r0 = (blockIdx.x & 63) << 6;
  int tid = threadIdx.x, w = tid >> 6, lane = tid & 63;
  const float* st = stats + (size_t)t * (2 * NREP * 64);
  if (tid < 64) {
    float s = 0.f, q = 0.f;
#pragma unroll
    for (int r2 = 0; r2 < NREP; ++r2) {
      s += st[r2 * 64 + tid];
      q += st[NREP * 64 + r2 * 64 + tid];
    }
    float mu = s * (1.0f / HD);
    float var = q * (1.0f / HD) - mu * mu;
    s_mu[tid] = mu;
    s_rs[tid] = rsqrtf(var + LN_EPS);
  }
  __syncthreads();
#pragma unroll
  for (int k = 0; k < 16; ++k) {
    int r = r0 + w * 16 + k;
    float a = __uint_as_float(((u32)A[((size_t)t * HD + r) * BB + lane]) << 16);
    float hn = (a - s_mu[lane]) * s_rs[lane] * gamma[r] + beta[r];
    tile[w * 16 + k][lane] = hn;
  }
  __syncthreads();
#pragma unroll
  for (int k = 0; k < 16; ++k) {
    int b = w * 16 + k;
    float v = tile[lane][b];
    out[((size_t)b * TT + t) * HD + r0 + lane] = v;
    if (t == TT - 1) out[(size_t)BB * TT * HD + (size_t)b * HD + r0 + lane] = v;
  }
}

// ---------------- host launch ----------------

extern "C" void kernel_launch(void* const* d_in, const int* in_sizes, int n_in,
                              void* d_out, int out_size, void* d_ws, size_t ws_size,
                              hipStream_t stream) {
  const float* x = (const float*)d_in[0];
  const int* ih_rows = (const int*)d_in[1];
  const int* ih_cols = (const int*)d_in[2];
  const float* ih_vals = (const float*)d_in[3];
  const int* hh_rows = (const int*)d_in[4];
  const int* hh_cols = (const int*)d_in[5];
  const float* hh_vals = (const float*)d_in[6];
  const float* b_ih = (const float*)d_in[7];
  const float* b_hh = (const float*)d_in[8];
  const float* gamma = (const float*)d_in[9];
  const float* beta = (const float*)d_in[10];

  char* ws = (char*)d_ws;
  // persistent regions
  u16* xt = (u16*)(ws + 0);                       // 16,777,216
  u16* A = (u16*)(ws + 16777216);                 // 67,108,864 (ends 83,886,080)
  u32* meta_ih = (u32*)(ws + 83886080);           // 1,179,904
  u32* meta_hh = (u32*)(ws + 85065984);           // 4,325,632
  float* stats = (float*)(ws + 89391616);         // 1,048,576
  float* rowvg = (float*)(ws + 90440192);         // 16,384
  float* rowvb = (float*)(ws + 90456576);         // 16,384
  int* rp_ih = (int*)(ws + 90472960);             // 16,640
  int* rp_hh = (int*)(ws + 90489600);             // 16,640  (end 90,506,240)

  // preprocessing scratch aliased into upper half of A (dead before first k_step)
  char* scr = ws + 50331648;
  int* hist_ih = (int*)(scr + 0);                 // 1,048,576
  int* hist_hh = (int*)(scr + 1048576);           // 1,048,576
  int* cur_ih = (int*)(scr + 2097152);            // 1,048,576
  int* cur_hh = (int*)(scr + 3145728);            // 1,048,576
  float* rvg_rep = (float*)(scr + 4194304);       // 1,048,576
  float* rvb_rep = (float*)(scr + 5242880);       // 1,048,576
  int* rowtot_ih = (int*)(scr + 6291456);         // 16,384
  int* rowtot_hh = (int*)(scr + 6307840);         // 16,384

  hipMemsetAsync(scr, 0, 6291456, stream);                    // hist + cur + reps
  hipMemsetAsync(ws + 83886080, 0, 6554112, stream);          // meta_ih + meta_hh + stats

  k_hist<<<N_IH / 256, 256, 0, stream>>>(ih_rows, N_IH, hist_ih);
  k_hist<<<N_HH / 256, 256, 0, stream>>>(hh_rows, N_HH, hist_hh);
  k_rowtot<<<HD / 4, 256, 0, stream>>>(hist_ih, rowtot_ih);
  k_rowtot<<<HD / 4, 256, 0, stream>>>(hist_hh, rowtot_hh);
  k_scan2<<<1, 64, 0, stream>>>(rowtot_ih, rp_ih);
  k_scan2<<<1, 64, 0, stream>>>(rowtot_hh, rp_hh);
  k_repbase<<<HD / 4, 256, 0, stream>>>(hist_ih, rp_ih, cur_ih);
  k_repbase<<<HD / 4, 256, 0, stream>>>(hist_hh, rp_hh, cur_hh);
  k_scatter<<<N_IH / 256, 256, 0, stream>>>(ih_rows, ih_cols, ih_vals, N_IH, cur_ih, meta_ih,
                                            gamma, beta, rvg_rep, rvb_rep, 0);
  k_scatter<<<N_HH / 256, 256, 0, stream>>>(hh_rows, hh_cols, hh_vals, N_HH, cur_hh, meta_hh,
                                            gamma, beta, rvg_rep, rvb_rep, 1);
  k_rvred<<<HD / 4, 256, 0, stream>>>(rvg_rep, rvb_rep, rowvg, rowvb);
  k_xt<<<TT * (II / 64), 256, 0, stream>>>(x, xt);

  for (int t = 0; t < TT; ++t) {
    const u16* xt_t = xt + (size_t)t * II * BB;
    const u16* Aprev = (t == 0) ? A : A + (size_t)(t - 1) * HD * BB;
    u16* Acur = A + (size_t)t * HD * BB;
    const float* st_prev = (t == 0) ? stats : stats + (size_t)(t - 1) * (2 * NREP * 64);
    float* st_cur = stats + (size_t)t * (2 * NREP * 64);
    k_step<<<HD / 2, 256, 0, stream>>>(meta_ih, rp_ih, meta_hh, rp_hh, xt_t, Aprev, Acur,
                                       st_prev, st_cur, b_ih, b_hh, rowvg, rowvb,
                                       (t == 0) ? 1 : 0);
  }

  k_out<<<TT * (HD / 64), 256, 0, stream>>>(A, stats, gamma, beta, (float*)d_out);
}

// Round 2
// 2329.719 us; speedup vs baseline: 1.3019x; 1.0690x over previous
//
#include <hip/hip_runtime.h>
#include <hip/hip_bf16.h>
#include <cstdint>

#define TT 128
#define BB 64
#define II 1024
#define HD 4096
#define N_IH 262144
#define N_HH 1048576
#define LN_EPS 1e-5f
#define NREP 16

typedef unsigned int u32;
typedef unsigned short u16;
typedef float f32x2 __attribute__((ext_vector_type(2)));

__device__ __forceinline__ u32 f2bf_bits(float f) {
  u32 u = __float_as_uint(f);
  return (u + 0x7FFFu + ((u >> 16) & 1u)) >> 16;   // RTNE, finite inputs
}

// ---------------- preprocessing ----------------

// replicated histogram: hist[row*64 + rep], rep = blockIdx & 63
__global__ void k_hist(const int* __restrict__ rows, int n, int* __restrict__ hist) {
  int e = blockIdx.x * 256 + threadIdx.x;
  if (e < n) atomicAdd(&hist[rows[e] * 64 + (blockIdx.x & 63)], 1);
}

// wave per row: padded row total
__global__ __launch_bounds__(256) void k_rowtot(const int* __restrict__ hist, int* __restrict__ rowtot) {
  int w = threadIdx.x >> 6, lane = threadIdx.x & 63;
  int row = blockIdx.x * 4 + w;
  int c = hist[row * 64 + lane];
#pragma unroll
  for (int d = 1; d < 64; d <<= 1) c += __shfl_xor(c, d);
  if (lane == 0) rowtot[row] = (c + 7) & ~7;
}

// one block, 64 threads: exclusive scan of 4096 padded row totals
__global__ void k_scan2(const int* __restrict__ rowtot, int* __restrict__ rp) {
  int lane = threadIdx.x;
  int total = 0;
  for (int j = 0; j < 64; ++j) total += rowtot[lane * 64 + j];
  int x = total;
  for (int d = 1; d < 64; d <<= 1) {
    int y = __shfl_up(x, d, 64);
    if (lane >= d) x += y;
  }
  int run = x - total;
  for (int j = 0; j < 64; ++j) {
    int idx = lane * 64 + j;
    rp[idx] = run;
    run += rowtot[idx];
  }
  if (lane == 63) rp[HD] = run;
}

// wave per row: cur[row*64+rep] = rp[row] + exclusive_scan(hist[row][*])
__global__ __launch_bounds__(256) void k_repbase(const int* __restrict__ hist, const int* __restrict__ rp,
                                                 int* __restrict__ cur) {
  int w = threadIdx.x >> 6, lane = threadIdx.x & 63;
  int row = blockIdx.x * 4 + w;
  int c = hist[row * 64 + lane];
  int x = c;
#pragma unroll
  for (int d = 1; d < 64; d <<= 1) {
    int y = __shfl_up(x, d, 64);
    if (lane >= d) x += y;
  }
  cur[row * 64 + lane] = rp[row] + (x - c);
}

__global__ void k_scatter(const int* __restrict__ rows, const int* __restrict__ cols,
                          const float* __restrict__ vals, int n,
                          int* __restrict__ cur, u32* __restrict__ meta,
                          const float* __restrict__ gamma, const float* __restrict__ beta,
                          float* __restrict__ rvg_rep, float* __restrict__ rvb_rep, int fold) {
  int e = blockIdx.x * 256 + threadIdx.x;
  if (e >= n) return;
  int rep = blockIdx.x & 63;
  int r = rows[e], c = cols[e];
  float v = vals[e];
  float vg = v;
  if (fold) {
    vg = v * gamma[c];
    atomicAdd(&rvg_rep[r * 64 + rep], vg);
    atomicAdd(&rvb_rep[r * 64 + rep], v * beta[c]);
  }
  u32 word = (f2bf_bits(vg) << 16) | (u32)c;
  int pos = atomicAdd(&cur[r * 64 + rep], 1);
  meta[pos] = word;
}

// wave per row: reduce 64 replicas -> rowvg/rowvb
__global__ __launch_bounds__(256) void k_rvred(const float* __restrict__ rvg_rep,
                                               const float* __restrict__ rvb_rep,
                                               float* __restrict__ rowvg, float* __restrict__ rowvb) {
  int w = threadIdx.x >> 6, lane = threadIdx.x & 63;
  int row = blockIdx.x * 4 + w;
  float a = rvg_rep[row * 64 + lane];
  float b = rvb_rep[row * 64 + lane];
#pragma unroll
  for (int d = 1; d < 64; d <<= 1) { a += __shfl_xor(a, d); b += __shfl_xor(b, d); }
  if (lane == 0) { rowvg[row] = a; rowvb[row] = b; }
}

// x (B,T,I) fp32 -> xt (T,I,B) bf16
__global__ __launch_bounds__(256) void k_xt(const float* __restrict__ x, u16* __restrict__ xt) {
  __shared__ u16 tile[64][66];
  int t = blockIdx.x >> 4, i0 = (blockIdx.x & 15) << 6;
  int w = threadIdx.x >> 6, lane = threadIdx.x & 63;
#pragma unroll
  for (int k = 0; k < 16; ++k) {
    int b = w * 16 + k;
    float v = x[((size_t)b * TT + t) * II + i0 + lane];
    tile[b][lane] = (u16)f2bf_bits(v);
  }
  __syncthreads();
#pragma unroll
  for (int k = 0; k < 16; ++k) {
    int i = w * 16 + k;
    xt[((size_t)t * II + i0 + i) * BB + lane] = tile[lane][i];
  }
}

// ---------------- per-step kernel ----------------

__device__ __forceinline__ uint4 gld(const char* base, u32 m) {
  return *(const uint4*)(base + ((int)(m & 0xFFFFu) << 7));
}

__device__ __forceinline__ void consume(u32 m, uint4 g, f32x2 acc[4]) {
  float vgf = __uint_as_float(m & 0xFFFF0000u);
  f32x2 vg2 = {vgf, vgf};
  f32x2 p0 = {__uint_as_float(g.x << 16), __uint_as_float(g.x & 0xFFFF0000u)};
  f32x2 p1 = {__uint_as_float(g.y << 16), __uint_as_float(g.y & 0xFFFF0000u)};
  f32x2 p2 = {__uint_as_float(g.z << 16), __uint_as_float(g.z & 0xFFFF0000u)};
  f32x2 p3 = {__uint_as_float(g.w << 16), __uint_as_float(g.w & 0xFFFF0000u)};
  acc[0] += vg2 * p0;
  acc[1] += vg2 * p1;
  acc[2] += vg2 * p2;
  acc[3] += vg2 * p3;
}

// Gather with meta in LDS: meta reads use lgkmcnt (separate HW counter), so the
// activation gathers keep true 4-5 deep MLP on vmcnt (no in-order collapse).
// lm points at this group's first meta dword in LDS; stride 8 dwords per iter.
// Meta is read 2 iterations ahead of its use as a gather address (~80 cy own
// issue + multi-wave covers ds_read latency ~120 cy).
__device__ __forceinline__ void gatherL(const u32* __restrict__ lm, int n,
                                        const char* __restrict__ base, f32x2 acc[4]) {
  if (n <= 0) return;
  u32 m0 = lm[0], m1 = lm[8], m2 = lm[16], m3 = lm[24], m4 = lm[32], m5 = lm[40];
  uint4 g0 = gld(base, m0), g1 = gld(base, m1), g2 = gld(base, m2), g3 = gld(base, m3);
#pragma unroll 4
  for (int it = 0; it < n; ++it) {
    u32 m6 = lm[(it + 6) * 8];          // ds_read, lgkmcnt path
    uint4 g4 = gld(base, m4);           // vmcnt path, address ready 2 iters ago
    consume(m0, g0, acc);
    m0 = m1; m1 = m2; m2 = m3; m3 = m4; m4 = m5; m5 = m6;
    g0 = g1; g1 = g2; g2 = g3; g3 = g4;
  }
}

// block = 4 waves = 2 rows, 2 waves per row (half each of IH and HH streams).
// grid HD/2 = 2048 blocks -> 8 blocks/CU -> 32 waves/CU.
// Meta for the block's rows is staged into LDS first (fixed-size chunks; slack
// reads land in zero padding / adjacent valid meta, cols <= 4095 -> safe addrs).
__global__ __launch_bounds__(256, 8) void k_step(
    const u32* __restrict__ meta_ih, const int* __restrict__ rp_ih,
    const u32* __restrict__ meta_hh, const int* __restrict__ rp_hh,
    const u16* __restrict__ xt_t, const u16* __restrict__ Aprev,
    u16* __restrict__ Acur,
    const float* __restrict__ st_prev, float* __restrict__ st_cur,
    const float* __restrict__ b_ih, const float* __restrict__ b_hh,
    const float* __restrict__ rowvg, const float* __restrict__ rowvb, int first) {
  __shared__ float s_mu[64], s_rs[64], s_sum[64], s_sq[64];
  __shared__ float epil[4][2][64];
  __shared__ __align__(16) u32 lmeta_hh[2][768];   // 6 KB: 768 edges/row cap (~3x mean)
  __shared__ __align__(16) u32 lmeta_ih[2][256];   // 2 KB: 256 edges/row cap (~4x mean)
  int tid = threadIdx.x;
  int w = tid >> 6, lane = tid & 63;
  int r0 = blockIdx.x * 2;

  // cooperative prologue: w0/w1 stage HH meta, w2 stages IH meta, w3 does LN stats
  if (w < 2) {
    if (!first) {
      int s0 = rp_hh[r0 + w];
      const uint4* src = (const uint4*)(meta_hh + s0);
      uint4* dst = (uint4*)(&lmeta_hh[w][0]);
#pragma unroll
      for (int k = 0; k < 3; ++k) dst[k * 64 + lane] = src[k * 64 + lane];
    }
  } else if (w == 2) {
#pragma unroll
    for (int i = 0; i < 2; ++i) {
      int s0 = rp_ih[r0 + i];
      ((uint4*)&lmeta_ih[i][0])[lane] = ((const uint4*)(meta_ih + s0))[lane];
    }
  } else {
    s_sum[lane] = 0.f;
    s_sq[lane] = 0.f;
    if (!first) {
      float s = 0.f, q = 0.f;
#pragma unroll
      for (int r2 = 0; r2 < NREP; ++r2) {
        s += st_prev[r2 * 64 + lane];
        q += st_prev[NREP * 64 + r2 * 64 + lane];
      }
      float mu = s * (1.0f / HD);
      float var = q * (1.0f / HD) - mu * mu;
      s_mu[lane] = mu;
      s_rs[lane] = rsqrtf(var + LN_EPS);
    }
  }
  __syncthreads();

  int row = r0 + (w >> 1);
  int half = w & 1;
  int grp = lane >> 3;
  int l = lane & 7;

  // ---- IH half ----
  f32x2 acc[4] = {{0,0},{0,0},{0,0},{0,0}};
  {
    int n = (rp_ih[row + 1] - rp_ih[row]) >> 3;
    int nA = (n + 1) >> 1;
    int nn = half ? (n - nA) : nA;
    const u32* lm = &lmeta_ih[w >> 1][(half ? nA * 8 : 0) + grp];
    gatherL(lm, nn, (const char*)xt_t + l * 16, acc);
  }
#pragma unroll
  for (int j = 0; j < 4; ++j) {
#pragma unroll
    for (int d = 8; d < 64; d <<= 1) {
      acc[j].x += __shfl_xor(acc[j].x, d);
      acc[j].y += __shfl_xor(acc[j].y, d);
    }
  }
  if (lane < 8) {
#pragma unroll
    for (int j = 0; j < 4; ++j) {
      epil[w][0][lane * 8 + 2 * j] = acc[j].x;
      epil[w][0][lane * 8 + 2 * j + 1] = acc[j].y;
    }
  }

  // ---- HH half ----
#pragma unroll
  for (int j = 0; j < 4; ++j) { acc[j].x = 0.f; acc[j].y = 0.f; }
  if (!first) {
    int n = (rp_hh[row + 1] - rp_hh[row]) >> 3;
    int nA = (n + 1) >> 1;
    int nn = half ? (n - nA) : nA;
    const u32* lm = &lmeta_hh[w >> 1][(half ? nA * 8 : 0) + grp];
    gatherL(lm, nn, (const char*)Aprev + l * 16, acc);
  }
#pragma unroll
  for (int j = 0; j < 4; ++j) {
#pragma unroll
    for (int d = 8; d < 64; d <<= 1) {
      acc[j].x += __shfl_xor(acc[j].x, d);
      acc[j].y += __shfl_xor(acc[j].y, d);
    }
  }
  if (lane < 8) {
#pragma unroll
    for (int j = 0; j < 4; ++j) {
      epil[w][1][lane * 8 + 2 * j] = acc[j].x;
      epil[w][1][lane * 8 + 2 * j + 1] = acc[j].y;
    }
  }

  __syncthreads();
  if (tid < 128) {
    int ridx = tid >> 6;
    int b = tid & 63;
    int row_e = r0 + ridx;
    float S_ih = epil[ridx * 2][0][b] + epil[ridx * 2 + 1][0][b];
    float bih = b_ih[row_e], bhh = b_hh[row_e];
    float pre;
    if (first) {
      pre = S_ih + bih + bhh;
    } else {
      float S_hh = epil[ridx * 2][1][b] + epil[ridx * 2 + 1][1][b];
      pre = S_ih + s_rs[b] * (S_hh - s_mu[b] * rowvg[row_e]) + (bih + bhh + rowvb[row_e]);
    }
    float h = 1.0f - 2.0f / (__expf(2.0f * pre) + 1.0f);   // tanh
    Acur[(size_t)row_e * BB + b] = (u16)f2bf_bits(h);
    atomicAdd(&s_sum[b], h);
    atomicAdd(&s_sq[b], h * h);
  }
  __syncthreads();
  if (tid < 64) {
    int rep = blockIdx.x & (NREP - 1);
    atomicAdd(&st_cur[rep * 64 + tid], s_sum[tid]);
    atomicAdd(&st_cur[NREP * 64 + rep * 64 + tid], s_sq[tid]);
  }
}

// ---------------- final output ----------------

__global__ __launch_bounds__(256) void k_out(const u16* __restrict__ A,
                                             const float* __restrict__ stats,
                                             const float* __restrict__ gamma,
                                             const float* __restrict__ beta,
                                             float* __restrict__ out) {
  __shared__ float s_mu[64], s_rs[64];
  __shared__ float tile[64][65];
  int t = blockIdx.x >> 6, r0 = (blockIdx.x & 63) << 6;
  int tid = threadIdx.x, w = tid >> 6, lane = tid & 63;
  const float* st = stats + (size_t)t * (2 * NREP * 64);
  if (tid < 64) {
    float s = 0.f, q = 0.f;
#pragma unroll
    for (int r2 = 0; r2 < NREP; ++r2) {
      s += st[r2 * 64 + tid];
      q += st[NREP * 64 + r2 * 64 + tid];
    }
    float mu = s * (1.0f / HD);
    float var = q * (1.0f / HD) - mu * mu;
    s_mu[tid] = mu;
    s_rs[tid] = rsqrtf(var + LN_EPS);
  }
  __syncthreads();
#pragma unroll
  for (int k = 0; k < 16; ++k) {
    int r = r0 + w * 16 + k;
    float a = __uint_as_float(((u32)A[((size_t)t * HD + r) * BB + lane]) << 16);
    float hn = (a - s_mu[lane]) * s_rs[lane] * gamma[r] + beta[r];
    tile[w * 16 + k][lane] = hn;
  }
  __syncthreads();
#pragma unroll
  for (int k = 0; k < 16; ++k) {
    int b = w * 16 + k;
    float v = tile[lane][b];
    out[((size_t)b * TT + t) * HD + r0 + lane] = v;
    if (t == TT - 1) out[(size_t)BB * TT * HD + (size_t)b * HD + r0 + lane] = v;
  }
}

// ---------------- host launch ----------------

extern "C" void kernel_launch(void* const* d_in, const int* in_sizes, int n_in,
                              void* d_out, int out_size, void* d_ws, size_t ws_size,
                              hipStream_t stream) {
  const float* x = (const float*)d_in[0];
  const int* ih_rows = (const int*)d_in[1];
  const int* ih_cols = (const int*)d_in[2];
  const float* ih_vals = (const float*)d_in[3];
  const int* hh_rows = (const int*)d_in[4];
  const int* hh_cols = (const int*)d_in[5];
  const float* hh_vals = (const float*)d_in[6];
  const float* b_ih = (const float*)d_in[7];
  const float* b_hh = (const float*)d_in[8];
  const float* gamma = (const float*)d_in[9];
  const float* beta = (const float*)d_in[10];

  char* ws = (char*)d_ws;
  // persistent regions
  u16* xt = (u16*)(ws + 0);                       // 16,777,216
  u16* A = (u16*)(ws + 16777216);                 // 67,108,864 (ends 83,886,080)
  u32* meta_ih = (u32*)(ws + 83886080);           // 1,179,904
  u32* meta_hh = (u32*)(ws + 85065984);           // 4,325,632
  float* stats = (float*)(ws + 89391616);         // 1,048,576
  float* rowvg = (float*)(ws + 90440192);         // 16,384
  float* rowvb = (float*)(ws + 90456576);         // 16,384
  int* rp_ih = (int*)(ws + 90472960);             // 16,640
  int* rp_hh = (int*)(ws + 90489600);             // 16,640  (end 90,506,240)

  // preprocessing scratch aliased into upper half of A (dead before first k_step)
  char* scr = ws + 50331648;
  int* hist_ih = (int*)(scr + 0);                 // 1,048,576
  int* hist_hh = (int*)(scr + 1048576);           // 1,048,576
  int* cur_ih = (int*)(scr + 2097152);            // 1,048,576
  int* cur_hh = (int*)(scr + 3145728);            // 1,048,576
  float* rvg_rep = (float*)(scr + 4194304);       // 1,048,576
  float* rvb_rep = (float*)(scr + 5242880);       // 1,048,576
  int* rowtot_ih = (int*)(scr + 6291456);         // 16,384
  int* rowtot_hh = (int*)(scr + 6307840);         // 16,384

  hipMemsetAsync(scr, 0, 6291456, stream);                    // hist + cur + reps
  hipMemsetAsync(ws + 83886080, 0, 6554112, stream);          // meta_ih + meta_hh + stats

  k_hist<<<N_IH / 256, 256, 0, stream>>>(ih_rows, N_IH, hist_ih);
  k_hist<<<N_HH / 256, 256, 0, stream>>>(hh_rows, N_HH, hist_hh);
  k_rowtot<<<HD / 4, 256, 0, stream>>>(hist_ih, rowtot_ih);
  k_rowtot<<<HD / 4, 256, 0, stream>>>(hist_hh, rowtot_hh);
  k_scan2<<<1, 64, 0, stream>>>(rowtot_ih, rp_ih);
  k_scan2<<<1, 64, 0, stream>>>(rowtot_hh, rp_hh);
  k_repbase<<<HD / 4, 256, 0, stream>>>(hist_ih, rp_ih, cur_ih);
  k_repbase<<<HD / 4, 256, 0, stream>>>(hist_hh, rp_hh, cur_hh);
  k_scatter<<<N_IH / 256, 256, 0, stream>>>(ih_rows, ih_cols, ih_vals, N_IH, cur_ih, meta_ih,
                                            gamma, beta, rvg_rep, rvb_rep, 0);
  k_scatter<<<N_HH / 256, 256, 0, stream>>>(hh_rows, hh_cols, hh_vals, N_HH, cur_hh, meta_hh,
                                            gamma, beta, rvg_rep, rvb_rep, 1);
  k_rvred<<<HD / 4, 256, 0, stream>>>(rvg_rep, rvb_rep, rowvg, rowvb);
  k_xt<<<TT * (II / 64), 256, 0, stream>>>(x, xt);

  for (int t = 0; t < TT; ++t) {
    const u16* xt_t = xt + (size_t)t * II * BB;
    const u16* Aprev = (t == 0) ? A : A + (size_t)(t - 1) * HD * BB;
    u16* Acur = A + (size_t)t * HD * BB;
    const float* st_prev = (t == 0) ? stats : stats + (size_t)(t - 1) * (2 * NREP * 64);
    float* st_cur = stats + (size_t)t * (2 * NREP * 64);
    k_step<<<HD / 2, 256, 0, stream>>>(meta_ih, rp_ih, meta_hh, rp_hh, xt_t, Aprev, Acur,
                                       st_prev, st_cur, b_ih, b_hh, rowvg, rowvb,
                                       (t == 0) ? 1 : 0);
  }

  k_out<<<TT * (HD / 64), 256, 0, stream>>>(A, stats, gamma, beta, (float*)d_out);
}